// Round 11
// baseline (140.808 us; speedup 1.0000x reference)
//
#include <hip/hip_runtime.h>

// ConvAttention2d: B=4, DIM=384, HEADS=8, DH=64, INNER=512, H=W=56, KS=3
// fp32 in/out. Internals: bf16 MFMA GEMMs (fp32 accum), blocked bf16 buffers.
// qkv = x @ [Wq;Wkv] -> 3x3 neighborhood attention -> out = ao @ Wo + bo
// R22: R20 base (best, 133.2us) + gemm1 coalesced epilogue: output tile
// staged in the dead staging-LDS as [plane(wm)][s][64d]; each plane is one
// CONTIGUOUS 16KB region of qkvT (row stride 64 = d width) -> each thread
// stores 128B thread-consecutive (was: 16x uint2 at 128B stride, 58MB
// written vs 38.5 ideal). Values bit-identical. K-loop = R20 (BK=64,
// plain __syncthreads -- R21's async pipeline was null).
// natt2 (R18 body) / gemm3 (R19) / cvt_all (R15) unchanged.

#define HW 3136
#define WIMG 56
#define QKV_CH 1536
#define SCALE 0.125f
#define KSTR 72            // natt LDS row stride in ushorts (144B)
#define NROWS 242          // staged rows: s0-57 .. s0+184
#define QKV_T 6422528      // one tensor: 4*8*3136*64 bf16 elems

typedef __bf16 bf16x8_t __attribute__((ext_vector_type(8)));
typedef float f32x4_t __attribute__((ext_vector_type(4)));
typedef unsigned short ushort8 __attribute__((ext_vector_type(8)));

__device__ __forceinline__ float bf2f(unsigned short u) {
    return __uint_as_float(((unsigned int)u) << 16);
}
__device__ __forceinline__ unsigned short f2bf(float f) {
    unsigned int u = __float_as_uint(f);
    u += 0x7FFFu + ((u >> 16) & 1u);   // round-to-nearest-even
    return (unsigned short)(u >> 16);
}

// async global->LDS, 16B per lane. LDS dest = wave-uniform base + lane*16.
__device__ __forceinline__ void gll16(const unsigned short* g, unsigned short* l) {
    __builtin_amdgcn_global_load_lds(
        (const __attribute__((address_space(1))) unsigned int*)g,
        (__attribute__((address_space(3))) unsigned int*)l,
        16, 0, 0);
}

// ---------------------------------------------------------------------------
// cvt_all (R15 verbatim): merged preprocessing.
// ---------------------------------------------------------------------------
__global__ __launch_bounds__(256) void cvt_all(
    const float* __restrict__ x,
    const float* __restrict__ Wq, const float* __restrict__ Wkv,
    const float* __restrict__ Wo,
    unsigned short* __restrict__ xT,
    unsigned short* __restrict__ wT, unsigned short* __restrict__ wT3)
{
    __shared__ unsigned short Tl[64 * 36];   // [s][c], pad 36 (cvtT_x branch only)
    const int bx = blockIdx.x;
    const int t = threadIdx.x;

    if (bx < 2400) {
        // ------- cvtT_x body -------
        const int sblk = bx % 50;
        const int kblk = (bx / 50) % 12;
        const int b    = bx / 600;

        if (sblk == 49) {               // zero-fill s in [3136,3200)
            unsigned short* dst = xT + (((size_t)b * 25 + 24) * 12 + kblk) * 4096 + 2048;
            *reinterpret_cast<uint4*>(dst + t * 8) = (uint4){0, 0, 0, 0};
            return;
        }

        const float* xp = x + ((size_t)b * 384 + (size_t)kblk * 32) * HW + sblk * 64;
        const int c = t >> 3;                    // 0..31
#pragma unroll
        for (int i = 0; i < 2; i++) {
            const int sc = (t & 7) + 8 * i;      // 0..15 (float4 chunks)
            const float4 v = *reinterpret_cast<const float4*>(xp + (size_t)c * HW + sc * 4);
            const int s4 = sc * 4;
            Tl[(s4 + 0) * 36 + c] = f2bf(v.x);
            Tl[(s4 + 1) * 36 + c] = f2bf(v.y);
            Tl[(s4 + 2) * 36 + c] = f2bf(v.z);
            Tl[(s4 + 3) * 36 + c] = f2bf(v.w);
        }
        __syncthreads();

        const int row = t >> 2, gran = t & 3;
        const uint2 lo = *reinterpret_cast<const uint2*>(&Tl[row * 36 + gran * 8]);
        const uint2 hi = *reinterpret_cast<const uint2*>(&Tl[row * 36 + gran * 8 + 4]);
        uint4 o; o.x = lo.x; o.y = lo.y; o.z = hi.x; o.w = hi.y;
        unsigned short* dst = xT + (((size_t)b * 25 + (sblk >> 1)) * 12 + kblk) * 4096
                            + (sblk & 1) * 2048;
        *reinterpret_cast<uint4*>(dst + t * 8) = o;
        return;
    }

    // ------- cvt_w body -------
    const int i = (bx - 2400) * 256 + t;
    if (i < 73728) {                    // wT: 12*12*128*4 uint4 slots
        const int g = i & 3;
        const int idx3 = i >> 2;        // [oblk][kb][o128]
        const int o128 = idx3 & 127;
        const int rest = idx3 >> 7;     // 0..143
        const int kb = rest % 12, oblk = rest / 12;
        const int o = oblk * 128 + o128;
        const int k0 = kb * 32 + g * 8;
        const float* src = (o < 512) ? (Wq + (size_t)o * 384 + k0)
                                     : (Wkv + (size_t)(o - 512) * 384 + k0);
        const float4 v0 = *reinterpret_cast<const float4*>(src);
        const float4 v1 = *reinterpret_cast<const float4*>(src + 4);
        uint4 u;
        u.x = (unsigned int)f2bf(v0.x) | ((unsigned int)f2bf(v0.y) << 16);
        u.y = (unsigned int)f2bf(v0.z) | ((unsigned int)f2bf(v0.w) << 16);
        u.z = (unsigned int)f2bf(v1.x) | ((unsigned int)f2bf(v1.y) << 16);
        u.w = (unsigned int)f2bf(v1.z) | ((unsigned int)f2bf(v1.w) << 16);
        reinterpret_cast<uint4*>(wT)[i] = u;
    } else {                            // wT3: 3*16*128*4 = 24576 uint4 slots
        const int j = i - 73728;        // [0, 24576)
        const int g = j & 3;
        const int idx3 = j >> 2;        // 0..6143
        const int o128 = idx3 & 127;
        const int rest = idx3 >> 7;     // 0..47
        const int kb = rest % 16, oblk = rest / 16;
        const int o = oblk * 128 + o128;            // < 384
        const float* src = Wo + (size_t)o * 512 + kb * 32 + g * 8;
        const float4 v0 = *reinterpret_cast<const float4*>(src);
        const float4 v1 = *reinterpret_cast<const float4*>(src + 4);
        uint4 u;
        u.x = (unsigned int)f2bf(v0.x) | ((unsigned int)f2bf(v0.y) << 16);
        u.y = (unsigned int)f2bf(v0.z) | ((unsigned int)f2bf(v0.w) << 16);
        u.z = (unsigned int)f2bf(v1.x) | ((unsigned int)f2bf(v1.y) << 16);
        u.w = (unsigned int)f2bf(v1.z) | ((unsigned int)f2bf(v1.w) << 16);
        reinterpret_cast<uint4*>(wT3)[j] = u;
    }
}

// ---------------------------------------------------------------------------
// GEMM1 (R22): R20 K-loop (BK=64, identity gload_lds, 2 barriers/step) +
// coalesced epilogue through the dead staging LDS. XCD-chunked grid.
// ---------------------------------------------------------------------------
__global__ __launch_bounds__(256) void gemm1(
    const unsigned short* __restrict__ xT,   // [b][25][12][128][32]
    const unsigned short* __restrict__ wT,   // [12][12][128][32]
    unsigned short* __restrict__ qkvT)       // [3][4][8][3136][64] bf16
{
    __shared__ __align__(16) unsigned short SMEM[16384];   // 32 KB
    unsigned short* A_lds = SMEM;            // [2][4096]
    unsigned short* B_lds = SMEM + 8192;     // [2][4096]

    const int lin = blockIdx.x;              // 0..1199
    const int swz = (lin & 7) * 150 + (lin >> 3);
    const int sblk = swz % 25;
    const int oblk = (swz / 25) % 12;
    const int b    = swz / 300;

    const int t  = threadIdx.x;
    const int lane = t & 63, w = t >> 6;
    const int quad = lane >> 4, mrow = lane & 15;
    const int wm = w >> 1, wn = w & 1;       // wave quadrant

    const unsigned short* wsrc = wT + ((size_t)oblk * 12) * 4096;
    const unsigned short* xsrc = xT + (((size_t)b * 25 + sblk) * 12) * 4096;

    f32x4_t acc[4][4];
#pragma unroll
    for (int m = 0; m < 4; m++)
#pragma unroll
        for (int n = 0; n < 4; n++) acc[m][n] = (f32x4_t){0.f, 0.f, 0.f, 0.f};

    for (int kb = 0; kb < 6; kb++) {
        const size_t k0 = (size_t)(2 * kb) * 4096;
        const size_t k1 = (size_t)(2 * kb + 1) * 4096;
        __syncthreads();   // previous iteration's fragment reads complete
        gll16(wsrc + k0 + t * 8,        A_lds + t * 8);
        gll16(wsrc + k0 + 2048 + t * 8, A_lds + 2048 + t * 8);
        gll16(wsrc + k1 + t * 8,        A_lds + 4096 + t * 8);
        gll16(wsrc + k1 + 2048 + t * 8, A_lds + 6144 + t * 8);
        gll16(xsrc + k0 + t * 8,        B_lds + t * 8);
        gll16(xsrc + k0 + 2048 + t * 8, B_lds + 2048 + t * 8);
        gll16(xsrc + k1 + t * 8,        B_lds + 4096 + t * 8);
        gll16(xsrc + k1 + 2048 + t * 8, B_lds + 6144 + t * 8);
        __syncthreads();   // drains vmcnt(0): both panels ready

#pragma unroll
        for (int ks = 0; ks < 2; ks++) {     // k ascending -> bit-exact
            bf16x8_t af[4], bfr[4];
#pragma unroll
            for (int m = 0; m < 4; m++)
                af[m] = *reinterpret_cast<const bf16x8_t*>(&A_lds[ks * 4096 + (wm * 64 + m * 16 + mrow) * 32 + quad * 8]);
#pragma unroll
            for (int n = 0; n < 4; n++)
                bfr[n] = *reinterpret_cast<const bf16x8_t*>(&B_lds[ks * 4096 + (wn * 64 + n * 16 + mrow) * 32 + quad * 8]);
#pragma unroll
            for (int m = 0; m < 4; m++)
#pragma unroll
                for (int n = 0; n < 4; n++)
                    acc[m][n] = __builtin_amdgcn_mfma_f32_16x16x32_bf16(af[m], bfr[n], acc[m][n], 0, 0, 0);
        }
    }

    // ---- coalesced epilogue: stage tile as [plane wm][s 128][d 64] ----
    __syncthreads();       // all waves done reading staging LDS
#pragma unroll
    for (int m = 0; m < 4; m++) {
#pragma unroll
        for (int n = 0; n < 4; n++) {
            const int srow = wn * 64 + n * 16 + mrow;
            unsigned short v[4];
            v[0] = f2bf(acc[m][n][0]); v[1] = f2bf(acc[m][n][1]);
            v[2] = f2bf(acc[m][n][2]); v[3] = f2bf(acc[m][n][3]);
            *reinterpret_cast<uint2*>(&SMEM[wm * 8192 + srow * 64 + m * 16 + quad * 4])
                = *reinterpret_cast<const uint2*>(v);
        }
    }
    __syncthreads();

    // plane p2 maps to one CONTIGUOUS region of qkvT (row stride = 64 = d
    // width). thread t: plane p2 = t>>7, row srow = t&127 -> 128B store.
    const int which = oblk >> 2;
    const int p2 = t >> 7, srow2 = t & 127;
    const int hq2 = (oblk & 3) * 2 + p2;
    const int sg = sblk * 128 + srow2;
    if (sg < HW) {
        unsigned short* gdst = qkvT + (size_t)which * QKV_T
                             + ((size_t)(b * 8 + hq2) * HW + sg) * 64;
        const unsigned short* lsrc = SMEM + p2 * 8192 + srow2 * 64;
#pragma unroll
        for (int c = 0; c < 8; c++) {
            const int c2 = (c + srow2) & 7;      // bank-stagger LDS reads
            *reinterpret_cast<uint4*>(gdst + c2 * 8)
                = *reinterpret_cast<const uint4*>(lsrc + c2 * 8);
        }
    }
}

// ---------------------------------------------------------------------------
// Neighborhood attention (R18 body, verbatim): 128-position blocks, dq-split,
// dred reduce, NROWS=242, K/V time-share. XCD-chunked 1D grid (800 blocks).
// ---------------------------------------------------------------------------
__global__ __launch_bounds__(256) void natt2(
    const unsigned short* __restrict__ qkvT, // [3][4][8][3136][64] bf16
    unsigned short* __restrict__ aoT)        // [4][49][16][64][32] bf16
{
    __shared__ __align__(16) unsigned short KV[NROWS * KSTR]; // K, then V (34.8 KB)
    __shared__ float dred[9 * 2 * 128];                       // 9.2 KB

    const int lin = blockIdx.x;          // 0..799
    const int swz = (lin & 7) * 100 + (lin >> 3);
    const int sblk = swz % 25;
    const int h = (swz / 25) & 7;
    const int b = swz / 200;

    const int t = threadIdx.x;
    const int p  = t & 127;              // position within block
    const int dq = t >> 7;               // 0,1: d-half (32 channels)
    const int s0 = sblk * 128;
    const int s  = s0 + p;               // may be >= HW in tail block
    const int sc = min(s, HW - 1);       // clamped for safe loads
    const int y  = sc / WIMG, xx = sc % WIMG;

    const unsigned short* qg = qkvT + ((size_t)(b * 8 + h) * HW) * 64;
    const unsigned short* kg = qg + (size_t)QKV_T;
    const unsigned short* vg = qg + (size_t)(2 * QKV_T);

    // ---- stage K: 242 rows x 8 chunks = 1936 uint4 ----
#pragma unroll
    for (int i = 0; i < 8; i++) {
        const int f = i * 256 + t;
        if (f < NROWS * 8) {
            const int row = f >> 3, c8 = f & 7;
            int srow = s0 - 57 + row;
            srow = min(max(srow, 0), HW - 1);
            const uint4 k4 = *reinterpret_cast<const uint4*>(kg + (size_t)srow * 64 + c8 * 8);
            *reinterpret_cast<uint4*>(&KV[row * KSTR + c8 * 8]) = k4;
        }
    }

    int   roff[9];
    float msk[9];
#pragma unroll
    for (int ty = 0; ty < 3; ty++)
#pragma unroll
        for (int tx = 0; tx < 3; tx++) {
            const int tap = ty * 3 + tx;
            const int ny = y + ty - 1, nx = xx + tx - 1;
            const bool v = (ny >= 0) && (ny < WIMG) && (nx >= 0) && (nx < WIMG);
            roff[tap] = (v ? ((ty - 1) * WIMG + (tx - 1)) : 0) * KSTR;
            msk[tap]  = v ? 1.f : 0.f;
        }

    // q: 32 channels for this (pos, dq) — 4 vectorized global loads
    float qv[32];
#pragma unroll
    for (int c = 0; c < 4; c++) {
        const uint4 q4 = *reinterpret_cast<const uint4*>(qg + (size_t)sc * 64 + dq * 32 + c * 8);
        qv[c*8+0] = bf2f((unsigned short)(q4.x & 0xffff)); qv[c*8+1] = bf2f((unsigned short)(q4.x >> 16));
        qv[c*8+2] = bf2f((unsigned short)(q4.y & 0xffff)); qv[c*8+3] = bf2f((unsigned short)(q4.y >> 16));
        qv[c*8+4] = bf2f((unsigned short)(q4.z & 0xffff)); qv[c*8+5] = bf2f((unsigned short)(q4.z >> 16));
        qv[c*8+6] = bf2f((unsigned short)(q4.w & 0xffff)); qv[c*8+7] = bf2f((unsigned short)(q4.w >> 16));
    }

    __syncthreads();                     // K staged

    const int rbase = (57 + p) * KSTR + dq * 32;

    float dots[9];
#pragma unroll
    for (int tp = 0; tp < 9; tp++) dots[tp] = 0.f;
#pragma unroll
    for (int ch = 0; ch < 4; ch++) {
#pragma unroll
        for (int tp = 0; tp < 9; tp++) {
            const ushort8 kk = *reinterpret_cast<const ushort8*>(&KV[rbase + roff[tp] + ch * 8]);
#pragma unroll
            for (int j = 0; j < 8; j++)
                dots[tp] += qv[ch * 8 + j] * bf2f(kk[j]);   // dd ascending per tap
        }
    }

    __syncthreads();                     // dots done: K buffer dead

    // dred partials + stage V into KV (K region dead)
#pragma unroll
    for (int tp = 0; tp < 9; tp++) dred[(tp * 2 + dq) * 128 + p] = dots[tp];
#pragma unroll
    for (int i = 0; i < 8; i++) {
        const int f = i * 256 + t;
        if (f < NROWS * 8) {
            const int row = f >> 3, c8 = f & 7;
            int srow = s0 - 57 + row;
            srow = min(max(srow, 0), HW - 1);
            const uint4 v4 = *reinterpret_cast<const uint4*>(vg + (size_t)srow * 64 + c8 * 8);
            *reinterpret_cast<uint4*>(&KV[row * KSTR + c8 * 8]) = v4;
        }
    }

    __syncthreads();                     // dred + V ready

    float mx = -1e30f, dt[9];
#pragma unroll
    for (int tp = 0; tp < 9; tp++) {
        const float sum = dred[(tp * 2 + 0) * 128 + p] + dred[(tp * 2 + 1) * 128 + p];
        dt[tp] = msk[tp] * (sum * SCALE);
        mx = fmaxf(mx, dt[tp]);
    }
    float se = 0.f, w9[9];
#pragma unroll
    for (int tp = 0; tp < 9; tp++) { w9[tp] = __expf(dt[tp] - mx); se += w9[tp]; }
    const float inv = 1.f / se;
#pragma unroll
    for (int tp = 0; tp < 9; tp++) w9[tp] *= inv * msk[tp];

    // PV: per 8-d chunk load 9 V fragments, accumulate tp-inner
    float o[32];
#pragma unroll
    for (int dd = 0; dd < 32; dd++) o[dd] = 0.f;
#pragma unroll
    for (int ch = 0; ch < 4; ch++) {
        ushort8 vfr[9];
#pragma unroll
        for (int tp = 0; tp < 9; tp++)
            vfr[tp] = *reinterpret_cast<const ushort8*>(&KV[rbase + roff[tp] + ch * 8]);
#pragma unroll
        for (int j = 0; j < 8; j++)
#pragma unroll
            for (int tp = 0; tp < 9; tp++)
                o[ch * 8 + j] += w9[tp] * bf2f(vfr[tp][j]);
    }

    if (s < HW) {
        __align__(16) unsigned short ov[32];
#pragma unroll
        for (int dd = 0; dd < 32; dd++) ov[dd] = f2bf(o[dd]);
        // blocked store: channels c = h*64 + dq*32 .. +32 -> kb = h*2+dq, col 0..32
        unsigned short* dst = aoT + (((size_t)(b * 49 + (s >> 6))) * 16 + (h * 2 + dq)) * 2048
                            + (s & 63) * 32;
        *reinterpret_cast<uint4*>(dst)      = *reinterpret_cast<const uint4*>(ov);
        *reinterpret_cast<uint4*>(dst + 8)  = *reinterpret_cast<const uint4*>(ov + 8);
        *reinterpret_cast<uint4*>(dst + 16) = *reinterpret_cast<const uint4*>(ov + 16);
        *reinterpret_cast<uint4*>(dst + 24) = *reinterpret_cast<const uint4*>(ov + 24);
    }
}

// ---------------------------------------------------------------------------
// GEMM3 (R19 verbatim): BK=64 + bijective XCD-chunked 1D grid (588 blocks,
// 4 XCDs x 74 + 4 XCDs x 73), oblk-fastest work order.
// ---------------------------------------------------------------------------
__global__ __launch_bounds__(256) void gemm3(
    const unsigned short* __restrict__ aoT,  // [4][49][16][64][32]
    const unsigned short* __restrict__ wT3,  // [3][16][128][32]
    const float* __restrict__ bias,          // (384)
    float* __restrict__ out)                 // (4,384,3136) f32
{
    __shared__ __align__(16) unsigned short A_lds[2][128 * 32];
    __shared__ __align__(16) unsigned short B_lds[2][64 * 32];

    // bijective XCD chunk: 588 = 4*74 + 4*73
    const int lin = blockIdx.x;              // 0..587
    const int xcd = lin & 7, idx = lin >> 3;
    const int wid = (xcd < 4) ? (xcd * 74 + idx) : (296 + (xcd - 4) * 73 + idx);
    const int oblk = wid % 3;                // oblk fastest: aoT tile shared
    const int sblk = (wid / 3) % 49;
    const int b    = wid / 147;

    const int t  = threadIdx.x;
    const int lane = t & 63, w = t >> 6;
    const int quad = lane >> 4, mrow = lane & 15;
    const int wm = w >> 1, wn = w & 1;       // wave: 64o x 32s quadrant

    const unsigned short* asrc = wT3 + (size_t)oblk * 16 * 4096;
    const unsigned short* bsrc = aoT + ((size_t)(b * 49 + sblk)) * 16 * 2048;

    f32x4_t acc[4][2];
#pragma unroll
    for (int m = 0; m < 4; m++)
#pragma unroll
        for (int n = 0; n < 2; n++) acc[m][n] = (f32x4_t){0.f, 0.f, 0.f, 0.f};

    for (int kb = 0; kb < 8; kb++) {
        const size_t a0 = (size_t)(2 * kb) * 4096;
        const size_t a1 = (size_t)(2 * kb + 1) * 4096;
        const size_t b0 = (size_t)(2 * kb) * 2048;
        const size_t b1 = (size_t)(2 * kb + 1) * 2048;
        __syncthreads();
        gll16(asrc + a0 + t * 8,        A_lds[0] + t * 8);
        gll16(asrc + a0 + 2048 + t * 8, A_lds[0] + 2048 + t * 8);
        gll16(asrc + a1 + t * 8,        A_lds[1] + t * 8);
        gll16(asrc + a1 + 2048 + t * 8, A_lds[1] + 2048 + t * 8);
        gll16(bsrc + b0 + t * 8,        B_lds[0] + t * 8);
        gll16(bsrc + b1 + t * 8,        B_lds[1] + t * 8);
        __syncthreads();

#pragma unroll
        for (int ks = 0; ks < 2; ks++) {     // k ascending -> bit-exact
            bf16x8_t af[4], bfr[2];
#pragma unroll
            for (int m = 0; m < 4; m++)
                af[m] = *reinterpret_cast<const bf16x8_t*>(&A_lds[ks][(wm * 64 + m * 16 + mrow) * 32 + quad * 8]);
#pragma unroll
            for (int n = 0; n < 2; n++)
                bfr[n] = *reinterpret_cast<const bf16x8_t*>(&B_lds[ks][(wn * 32 + n * 16 + mrow) * 32 + quad * 8]);
#pragma unroll
            for (int m = 0; m < 4; m++)
#pragma unroll
                for (int n = 0; n < 2; n++)
                    acc[m][n] = __builtin_amdgcn_mfma_f32_16x16x32_bf16(af[m], bfr[n], acc[m][n], 0, 0, 0);
        }
    }

    const int o0 = oblk * 128 + wm * 64;
    const int s0 = sblk * 64 + wn * 32;
    float* outb = out + (size_t)b * 384 * HW;
#pragma unroll
    for (int m = 0; m < 4; m++)
#pragma unroll
        for (int n = 0; n < 2; n++) {
            const int ss = s0 + n * 16 + mrow;      // < 3136 always (49*64 exact)
#pragma unroll
            for (int r = 0; r < 4; r++) {
                const int oo = o0 + m * 16 + quad * 4 + r;
                outb[(size_t)oo * HW + ss] = acc[m][n][r] + bias[oo];
            }
        }
}

extern "C" void kernel_launch(void* const* d_in, const int* in_sizes, int n_in,
                              void* d_out, int out_size, void* d_ws, size_t ws_size,
                              hipStream_t stream) {
    const float* x   = (const float*)d_in[0];
    const float* Wq  = (const float*)d_in[1];
    const float* Wkv = (const float*)d_in[2];
    const float* Wo  = (const float*)d_in[3];
    const float* bo  = (const float*)d_in[4];
    float* out = (float*)d_out;

    // ws layout (bf16 elements)
    unsigned short* xT   = (unsigned short*)d_ws;                 // 4*25*12*4096 = 4,915,200
    unsigned short* wT   = xT + (size_t)4915200;                  // 12*12*128*32 =   589,824
    unsigned short* wT3  = wT + (size_t)589824;                   // 3*16*128*32  =   196,608
    unsigned short* qkvT = wT3 + (size_t)196608;                  // 3*4*8*3136*64 = 19,267,584
    unsigned short* aoT  = qkvT + (size_t)(3 * QKV_T);            // 4*49*16*2048 =  6,422,528

    // one merged preprocessing dispatch: 2400 cvtT_x blocks + 384 cvt_w blocks
    cvt_all<<<dim3(2784), 256, 0, stream>>>(x, Wq, Wkv, Wo, xT, wT, wT3);

    gemm1<<<dim3(1200), 256, 0, stream>>>(xT, wT, qkvT);
    natt2<<<dim3(800), 256, 0, stream>>>(qkvT, aoT);
    gemm3<<<dim3(588), 256, 0, stream>>>(aoT, wT3, bo, out);
}

// Round 12
// 129.721 us; speedup vs baseline: 1.0855x; 1.0855x over previous
//
#include <hip/hip_runtime.h>

// ConvAttention2d: B=4, DIM=384, HEADS=8, DH=64, INNER=512, H=W=56, KS=3
// fp32 in/out. Internals: bf16 MFMA GEMMs (fp32 accum), blocked bf16 buffers.
// qkv = x @ [Wq;Wkv] -> 3x3 neighborhood attention -> out = ao @ Wo + bo
// R23: R20 base + gemm1 coalesced epilogue, FIXED vs R22's two bugs:
//  - LDS staging of the output tile uses a chunk XOR-swizzle (chunk ^ srow&7)
//    -> write conflicts 16-way -> ~4-way (R22: 128B-stride all-same-bank).
//  - global stores are lane-contiguous: thread f=(i*256+t) -> (plane f>>10,
//    row (f>>3)&127, chunk f&7); each wave instr writes 1KB contiguous
//    (R22's stagger scattered 16B per 128B row).
// Values bit-identical. K-loop = R20 (BK=64, plain __syncthreads).
// natt2 (R18 body) / gemm3 (R19) / cvt_all (R15) unchanged.

#define HW 3136
#define WIMG 56
#define QKV_CH 1536
#define SCALE 0.125f
#define KSTR 72            // natt LDS row stride in ushorts (144B)
#define NROWS 242          // staged rows: s0-57 .. s0+184
#define QKV_T 6422528      // one tensor: 4*8*3136*64 bf16 elems

typedef __bf16 bf16x8_t __attribute__((ext_vector_type(8)));
typedef float f32x4_t __attribute__((ext_vector_type(4)));
typedef unsigned short ushort8 __attribute__((ext_vector_type(8)));

__device__ __forceinline__ float bf2f(unsigned short u) {
    return __uint_as_float(((unsigned int)u) << 16);
}
__device__ __forceinline__ unsigned short f2bf(float f) {
    unsigned int u = __float_as_uint(f);
    u += 0x7FFFu + ((u >> 16) & 1u);   // round-to-nearest-even
    return (unsigned short)(u >> 16);
}

// async global->LDS, 16B per lane. LDS dest = wave-uniform base + lane*16.
__device__ __forceinline__ void gll16(const unsigned short* g, unsigned short* l) {
    __builtin_amdgcn_global_load_lds(
        (const __attribute__((address_space(1))) unsigned int*)g,
        (__attribute__((address_space(3))) unsigned int*)l,
        16, 0, 0);
}

// ---------------------------------------------------------------------------
// cvt_all (R15 verbatim): merged preprocessing.
// ---------------------------------------------------------------------------
__global__ __launch_bounds__(256) void cvt_all(
    const float* __restrict__ x,
    const float* __restrict__ Wq, const float* __restrict__ Wkv,
    const float* __restrict__ Wo,
    unsigned short* __restrict__ xT,
    unsigned short* __restrict__ wT, unsigned short* __restrict__ wT3)
{
    __shared__ unsigned short Tl[64 * 36];   // [s][c], pad 36 (cvtT_x branch only)
    const int bx = blockIdx.x;
    const int t = threadIdx.x;

    if (bx < 2400) {
        // ------- cvtT_x body -------
        const int sblk = bx % 50;
        const int kblk = (bx / 50) % 12;
        const int b    = bx / 600;

        if (sblk == 49) {               // zero-fill s in [3136,3200)
            unsigned short* dst = xT + (((size_t)b * 25 + 24) * 12 + kblk) * 4096 + 2048;
            *reinterpret_cast<uint4*>(dst + t * 8) = (uint4){0, 0, 0, 0};
            return;
        }

        const float* xp = x + ((size_t)b * 384 + (size_t)kblk * 32) * HW + sblk * 64;
        const int c = t >> 3;                    // 0..31
#pragma unroll
        for (int i = 0; i < 2; i++) {
            const int sc = (t & 7) + 8 * i;      // 0..15 (float4 chunks)
            const float4 v = *reinterpret_cast<const float4*>(xp + (size_t)c * HW + sc * 4);
            const int s4 = sc * 4;
            Tl[(s4 + 0) * 36 + c] = f2bf(v.x);
            Tl[(s4 + 1) * 36 + c] = f2bf(v.y);
            Tl[(s4 + 2) * 36 + c] = f2bf(v.z);
            Tl[(s4 + 3) * 36 + c] = f2bf(v.w);
        }
        __syncthreads();

        const int row = t >> 2, gran = t & 3;
        const uint2 lo = *reinterpret_cast<const uint2*>(&Tl[row * 36 + gran * 8]);
        const uint2 hi = *reinterpret_cast<const uint2*>(&Tl[row * 36 + gran * 8 + 4]);
        uint4 o; o.x = lo.x; o.y = lo.y; o.z = hi.x; o.w = hi.y;
        unsigned short* dst = xT + (((size_t)b * 25 + (sblk >> 1)) * 12 + kblk) * 4096
                            + (sblk & 1) * 2048;
        *reinterpret_cast<uint4*>(dst + t * 8) = o;
        return;
    }

    // ------- cvt_w body -------
    const int i = (bx - 2400) * 256 + t;
    if (i < 73728) {                    // wT: 12*12*128*4 uint4 slots
        const int g = i & 3;
        const int idx3 = i >> 2;        // [oblk][kb][o128]
        const int o128 = idx3 & 127;
        const int rest = idx3 >> 7;     // 0..143
        const int kb = rest % 12, oblk = rest / 12;
        const int o = oblk * 128 + o128;
        const int k0 = kb * 32 + g * 8;
        const float* src = (o < 512) ? (Wq + (size_t)o * 384 + k0)
                                     : (Wkv + (size_t)(o - 512) * 384 + k0);
        const float4 v0 = *reinterpret_cast<const float4*>(src);
        const float4 v1 = *reinterpret_cast<const float4*>(src + 4);
        uint4 u;
        u.x = (unsigned int)f2bf(v0.x) | ((unsigned int)f2bf(v0.y) << 16);
        u.y = (unsigned int)f2bf(v0.z) | ((unsigned int)f2bf(v0.w) << 16);
        u.z = (unsigned int)f2bf(v1.x) | ((unsigned int)f2bf(v1.y) << 16);
        u.w = (unsigned int)f2bf(v1.z) | ((unsigned int)f2bf(v1.w) << 16);
        reinterpret_cast<uint4*>(wT)[i] = u;
    } else {                            // wT3: 3*16*128*4 = 24576 uint4 slots
        const int j = i - 73728;        // [0, 24576)
        const int g = j & 3;
        const int idx3 = j >> 2;        // 0..6143
        const int o128 = idx3 & 127;
        const int rest = idx3 >> 7;     // 0..47
        const int kb = rest % 16, oblk = rest / 16;
        const int o = oblk * 128 + o128;            // < 384
        const float* src = Wo + (size_t)o * 512 + kb * 32 + g * 8;
        const float4 v0 = *reinterpret_cast<const float4*>(src);
        const float4 v1 = *reinterpret_cast<const float4*>(src + 4);
        uint4 u;
        u.x = (unsigned int)f2bf(v0.x) | ((unsigned int)f2bf(v0.y) << 16);
        u.y = (unsigned int)f2bf(v0.z) | ((unsigned int)f2bf(v0.w) << 16);
        u.z = (unsigned int)f2bf(v1.x) | ((unsigned int)f2bf(v1.y) << 16);
        u.w = (unsigned int)f2bf(v1.z) | ((unsigned int)f2bf(v1.w) << 16);
        reinterpret_cast<uint4*>(wT3)[j] = u;
    }
}

// ---------------------------------------------------------------------------
// GEMM1 (R23): R20 K-loop (BK=64, identity gload_lds, 2 barriers/step) +
// fixed coalesced epilogue (swizzled LDS stage, contiguous global stores).
// XCD-chunked grid (1200 blocks, 150/XCD).
// ---------------------------------------------------------------------------
__global__ __launch_bounds__(256) void gemm1(
    const unsigned short* __restrict__ xT,   // [b][25][12][128][32]
    const unsigned short* __restrict__ wT,   // [12][12][128][32]
    unsigned short* __restrict__ qkvT)       // [3][4][8][3136][64] bf16
{
    __shared__ __align__(16) unsigned short SMEM[16384];   // 32 KB
    unsigned short* A_lds = SMEM;            // [2][4096]
    unsigned short* B_lds = SMEM + 8192;     // [2][4096]

    const int lin = blockIdx.x;              // 0..1199
    const int swz = (lin & 7) * 150 + (lin >> 3);
    const int sblk = swz % 25;
    const int oblk = (swz / 25) % 12;
    const int b    = swz / 300;

    const int t  = threadIdx.x;
    const int lane = t & 63, w = t >> 6;
    const int quad = lane >> 4, mrow = lane & 15;
    const int wm = w >> 1, wn = w & 1;       // wave quadrant

    const unsigned short* wsrc = wT + ((size_t)oblk * 12) * 4096;
    const unsigned short* xsrc = xT + (((size_t)b * 25 + sblk) * 12) * 4096;

    f32x4_t acc[4][4];
#pragma unroll
    for (int m = 0; m < 4; m++)
#pragma unroll
        for (int n = 0; n < 4; n++) acc[m][n] = (f32x4_t){0.f, 0.f, 0.f, 0.f};

    for (int kb = 0; kb < 6; kb++) {
        const size_t k0 = (size_t)(2 * kb) * 4096;
        const size_t k1 = (size_t)(2 * kb + 1) * 4096;
        __syncthreads();   // previous iteration's fragment reads complete
        gll16(wsrc + k0 + t * 8,        A_lds + t * 8);
        gll16(wsrc + k0 + 2048 + t * 8, A_lds + 2048 + t * 8);
        gll16(wsrc + k1 + t * 8,        A_lds + 4096 + t * 8);
        gll16(wsrc + k1 + 2048 + t * 8, A_lds + 6144 + t * 8);
        gll16(xsrc + k0 + t * 8,        B_lds + t * 8);
        gll16(xsrc + k0 + 2048 + t * 8, B_lds + 2048 + t * 8);
        gll16(xsrc + k1 + t * 8,        B_lds + 4096 + t * 8);
        gll16(xsrc + k1 + 2048 + t * 8, B_lds + 6144 + t * 8);
        __syncthreads();   // drains vmcnt(0): both panels ready

#pragma unroll
        for (int ks = 0; ks < 2; ks++) {     // k ascending -> bit-exact
            bf16x8_t af[4], bfr[4];
#pragma unroll
            for (int m = 0; m < 4; m++)
                af[m] = *reinterpret_cast<const bf16x8_t*>(&A_lds[ks * 4096 + (wm * 64 + m * 16 + mrow) * 32 + quad * 8]);
#pragma unroll
            for (int n = 0; n < 4; n++)
                bfr[n] = *reinterpret_cast<const bf16x8_t*>(&B_lds[ks * 4096 + (wn * 64 + n * 16 + mrow) * 32 + quad * 8]);
#pragma unroll
            for (int m = 0; m < 4; m++)
#pragma unroll
                for (int n = 0; n < 4; n++)
                    acc[m][n] = __builtin_amdgcn_mfma_f32_16x16x32_bf16(af[m], bfr[n], acc[m][n], 0, 0, 0);
        }
    }

    // ---- epilogue: stage tile [plane wm][srow 128][d 64] with 16B-chunk
    // XOR-swizzle (chunk ^ (srow&7)); then contiguous global stores.
    __syncthreads();       // all waves done reading staging LDS
#pragma unroll
    for (int m = 0; m < 4; m++) {
        const int chunkw = m * 2 + (quad >> 1);   // d>>3
        const int half   = quad & 1;              // which 8B of the 16B chunk
#pragma unroll
        for (int n = 0; n < 4; n++) {
            const int srow = wn * 64 + n * 16 + mrow;
            unsigned short v[4];
            v[0] = f2bf(acc[m][n][0]); v[1] = f2bf(acc[m][n][1]);
            v[2] = f2bf(acc[m][n][2]); v[3] = f2bf(acc[m][n][3]);
            *reinterpret_cast<uint2*>(&SMEM[wm * 8192 + srow * 64
                + ((chunkw ^ (srow & 7)) << 3) + half * 4])
                = *reinterpret_cast<const uint2*>(v);
        }
    }
    __syncthreads();

    // global: f = i*256+t -> plane f>>10, row (f>>3)&127, chunk f&7.
    // Wave's 64 lanes -> 1KB contiguous qkvT run per instruction.
    const int which = oblk >> 2;
#pragma unroll
    for (int i = 0; i < 8; i++) {
        const int f = i * 256 + t;           // 0..2047
        const int plane = f >> 10;           // 0,1 (= wm of producer)
        const int row   = (f >> 3) & 127;
        const int chunk = f & 7;
        const int hq2 = (oblk & 3) * 2 + plane;
        const int sg  = sblk * 128 + row;
        if (sg < HW) {
            const unsigned short* lsrc = SMEM + plane * 8192 + row * 64
                                       + ((chunk ^ (row & 7)) << 3);
            unsigned short* gdst = qkvT + (size_t)which * QKV_T
                                 + ((size_t)(b * 8 + hq2) * HW + sg) * 64 + chunk * 8;
            *reinterpret_cast<uint4*>(gdst) = *reinterpret_cast<const uint4*>(lsrc);
        }
    }
}

// ---------------------------------------------------------------------------
// Neighborhood attention (R18 body, verbatim): 128-position blocks, dq-split,
// dred reduce, NROWS=242, K/V time-share. XCD-chunked 1D grid (800 blocks).
// ---------------------------------------------------------------------------
__global__ __launch_bounds__(256) void natt2(
    const unsigned short* __restrict__ qkvT, // [3][4][8][3136][64] bf16
    unsigned short* __restrict__ aoT)        // [4][49][16][64][32] bf16
{
    __shared__ __align__(16) unsigned short KV[NROWS * KSTR]; // K, then V (34.8 KB)
    __shared__ float dred[9 * 2 * 128];                       // 9.2 KB

    const int lin = blockIdx.x;          // 0..799
    const int swz = (lin & 7) * 100 + (lin >> 3);
    const int sblk = swz % 25;
    const int h = (swz / 25) & 7;
    const int b = swz / 200;

    const int t = threadIdx.x;
    const int p  = t & 127;              // position within block
    const int dq = t >> 7;               // 0,1: d-half (32 channels)
    const int s0 = sblk * 128;
    const int s  = s0 + p;               // may be >= HW in tail block
    const int sc = min(s, HW - 1);       // clamped for safe loads
    const int y  = sc / WIMG, xx = sc % WIMG;

    const unsigned short* qg = qkvT + ((size_t)(b * 8 + h) * HW) * 64;
    const unsigned short* kg = qg + (size_t)QKV_T;
    const unsigned short* vg = qg + (size_t)(2 * QKV_T);

    // ---- stage K: 242 rows x 8 chunks = 1936 uint4 ----
#pragma unroll
    for (int i = 0; i < 8; i++) {
        const int f = i * 256 + t;
        if (f < NROWS * 8) {
            const int row = f >> 3, c8 = f & 7;
            int srow = s0 - 57 + row;
            srow = min(max(srow, 0), HW - 1);
            const uint4 k4 = *reinterpret_cast<const uint4*>(kg + (size_t)srow * 64 + c8 * 8);
            *reinterpret_cast<uint4*>(&KV[row * KSTR + c8 * 8]) = k4;
        }
    }

    int   roff[9];
    float msk[9];
#pragma unroll
    for (int ty = 0; ty < 3; ty++)
#pragma unroll
        for (int tx = 0; tx < 3; tx++) {
            const int tap = ty * 3 + tx;
            const int ny = y + ty - 1, nx = xx + tx - 1;
            const bool v = (ny >= 0) && (ny < WIMG) && (nx >= 0) && (nx < WIMG);
            roff[tap] = (v ? ((ty - 1) * WIMG + (tx - 1)) : 0) * KSTR;
            msk[tap]  = v ? 1.f : 0.f;
        }

    // q: 32 channels for this (pos, dq) — 4 vectorized global loads
    float qv[32];
#pragma unroll
    for (int c = 0; c < 4; c++) {
        const uint4 q4 = *reinterpret_cast<const uint4*>(qg + (size_t)sc * 64 + dq * 32 + c * 8);
        qv[c*8+0] = bf2f((unsigned short)(q4.x & 0xffff)); qv[c*8+1] = bf2f((unsigned short)(q4.x >> 16));
        qv[c*8+2] = bf2f((unsigned short)(q4.y & 0xffff)); qv[c*8+3] = bf2f((unsigned short)(q4.y >> 16));
        qv[c*8+4] = bf2f((unsigned short)(q4.z & 0xffff)); qv[c*8+5] = bf2f((unsigned short)(q4.z >> 16));
        qv[c*8+6] = bf2f((unsigned short)(q4.w & 0xffff)); qv[c*8+7] = bf2f((unsigned short)(q4.w >> 16));
    }

    __syncthreads();                     // K staged

    const int rbase = (57 + p) * KSTR + dq * 32;

    float dots[9];
#pragma unroll
    for (int tp = 0; tp < 9; tp++) dots[tp] = 0.f;
#pragma unroll
    for (int ch = 0; ch < 4; ch++) {
#pragma unroll
        for (int tp = 0; tp < 9; tp++) {
            const ushort8 kk = *reinterpret_cast<const ushort8*>(&KV[rbase + roff[tp] + ch * 8]);
#pragma unroll
            for (int j = 0; j < 8; j++)
                dots[tp] += qv[ch * 8 + j] * bf2f(kk[j]);   // dd ascending per tap
        }
    }

    __syncthreads();                     // dots done: K buffer dead

    // dred partials + stage V into KV (K region dead)
#pragma unroll
    for (int tp = 0; tp < 9; tp++) dred[(tp * 2 + dq) * 128 + p] = dots[tp];
#pragma unroll
    for (int i = 0; i < 8; i++) {
        const int f = i * 256 + t;
        if (f < NROWS * 8) {
            const int row = f >> 3, c8 = f & 7;
            int srow = s0 - 57 + row;
            srow = min(max(srow, 0), HW - 1);
            const uint4 v4 = *reinterpret_cast<const uint4*>(vg + (size_t)srow * 64 + c8 * 8);
            *reinterpret_cast<uint4*>(&KV[row * KSTR + c8 * 8]) = v4;
        }
    }

    __syncthreads();                     // dred + V ready

    float mx = -1e30f, dt[9];
#pragma unroll
    for (int tp = 0; tp < 9; tp++) {
        const float sum = dred[(tp * 2 + 0) * 128 + p] + dred[(tp * 2 + 1) * 128 + p];
        dt[tp] = msk[tp] * (sum * SCALE);
        mx = fmaxf(mx, dt[tp]);
    }
    float se = 0.f, w9[9];
#pragma unroll
    for (int tp = 0; tp < 9; tp++) { w9[tp] = __expf(dt[tp] - mx); se += w9[tp]; }
    const float inv = 1.f / se;
#pragma unroll
    for (int tp = 0; tp < 9; tp++) w9[tp] *= inv * msk[tp];

    // PV: per 8-d chunk load 9 V fragments, accumulate tp-inner
    float o[32];
#pragma unroll
    for (int dd = 0; dd < 32; dd++) o[dd] = 0.f;
#pragma unroll
    for (int ch = 0; ch < 4; ch++) {
        ushort8 vfr[9];
#pragma unroll
        for (int tp = 0; tp < 9; tp++)
            vfr[tp] = *reinterpret_cast<const ushort8*>(&KV[rbase + roff[tp] + ch * 8]);
#pragma unroll
        for (int j = 0; j < 8; j++)
#pragma unroll
            for (int tp = 0; tp < 9; tp++)
                o[ch * 8 + j] += w9[tp] * bf2f(vfr[tp][j]);
    }

    if (s < HW) {
        __align__(16) unsigned short ov[32];
#pragma unroll
        for (int dd = 0; dd < 32; dd++) ov[dd] = f2bf(o[dd]);
        // blocked store: channels c = h*64 + dq*32 .. +32 -> kb = h*2+dq, col 0..32
        unsigned short* dst = aoT + (((size_t)(b * 49 + (s >> 6))) * 16 + (h * 2 + dq)) * 2048
                            + (s & 63) * 32;
        *reinterpret_cast<uint4*>(dst)      = *reinterpret_cast<const uint4*>(ov);
        *reinterpret_cast<uint4*>(dst + 8)  = *reinterpret_cast<const uint4*>(ov + 8);
        *reinterpret_cast<uint4*>(dst + 16) = *reinterpret_cast<const uint4*>(ov + 16);
        *reinterpret_cast<uint4*>(dst + 24) = *reinterpret_cast<const uint4*>(ov + 24);
    }
}

// ---------------------------------------------------------------------------
// GEMM3 (R19 verbatim): BK=64 + bijective XCD-chunked 1D grid (588 blocks,
// 4 XCDs x 74 + 4 XCDs x 73), oblk-fastest work order.
// ---------------------------------------------------------------------------
__global__ __launch_bounds__(256) void gemm3(
    const unsigned short* __restrict__ aoT,  // [4][49][16][64][32]
    const unsigned short* __restrict__ wT3,  // [3][16][128][32]
    const float* __restrict__ bias,          // (384)
    float* __restrict__ out)                 // (4,384,3136) f32
{
    __shared__ __align__(16) unsigned short A_lds[2][128 * 32];
    __shared__ __align__(16) unsigned short B_lds[2][64 * 32];

    // bijective XCD chunk: 588 = 4*74 + 4*73
    const int lin = blockIdx.x;              // 0..587
    const int xcd = lin & 7, idx = lin >> 3;
    const int wid = (xcd < 4) ? (xcd * 74 + idx) : (296 + (xcd - 4) * 73 + idx);
    const int oblk = wid % 3;                // oblk fastest: aoT tile shared
    const int sblk = (wid / 3) % 49;
    const int b    = wid / 147;

    const int t  = threadIdx.x;
    const int lane = t & 63, w = t >> 6;
    const int quad = lane >> 4, mrow = lane & 15;
    const int wm = w >> 1, wn = w & 1;       // wave: 64o x 32s quadrant

    const unsigned short* asrc = wT3 + (size_t)oblk * 16 * 4096;
    const unsigned short* bsrc = aoT + ((size_t)(b * 49 + sblk)) * 16 * 2048;

    f32x4_t acc[4][2];
#pragma unroll
    for (int m = 0; m < 4; m++)
#pragma unroll
        for (int n = 0; n < 2; n++) acc[m][n] = (f32x4_t){0.f, 0.f, 0.f, 0.f};

    for (int kb = 0; kb < 8; kb++) {
        const size_t a0 = (size_t)(2 * kb) * 4096;
        const size_t a1 = (size_t)(2 * kb + 1) * 4096;
        const size_t b0 = (size_t)(2 * kb) * 2048;
        const size_t b1 = (size_t)(2 * kb + 1) * 2048;
        __syncthreads();
        gll16(asrc + a0 + t * 8,        A_lds[0] + t * 8);
        gll16(asrc + a0 + 2048 + t * 8, A_lds[0] + 2048 + t * 8);
        gll16(asrc + a1 + t * 8,        A_lds[1] + t * 8);
        gll16(asrc + a1 + 2048 + t * 8, A_lds[1] + 2048 + t * 8);
        gll16(bsrc + b0 + t * 8,        B_lds[0] + t * 8);
        gll16(bsrc + b1 + t * 8,        B_lds[1] + t * 8);
        __syncthreads();

#pragma unroll
        for (int ks = 0; ks < 2; ks++) {     // k ascending -> bit-exact
            bf16x8_t af[4], bfr[2];
#pragma unroll
            for (int m = 0; m < 4; m++)
                af[m] = *reinterpret_cast<const bf16x8_t*>(&A_lds[ks][(wm * 64 + m * 16 + mrow) * 32 + quad * 8]);
#pragma unroll
            for (int n = 0; n < 2; n++)
                bfr[n] = *reinterpret_cast<const bf16x8_t*>(&B_lds[ks][(wn * 32 + n * 16 + mrow) * 32 + quad * 8]);
#pragma unroll
            for (int m = 0; m < 4; m++)
#pragma unroll
                for (int n = 0; n < 2; n++)
                    acc[m][n] = __builtin_amdgcn_mfma_f32_16x16x32_bf16(af[m], bfr[n], acc[m][n], 0, 0, 0);
        }
    }

    const int o0 = oblk * 128 + wm * 64;
    const int s0 = sblk * 64 + wn * 32;
    float* outb = out + (size_t)b * 384 * HW;
#pragma unroll
    for (int m = 0; m < 4; m++)
#pragma unroll
        for (int n = 0; n < 2; n++) {
            const int ss = s0 + n * 16 + mrow;      // < 3136 always (49*64 exact)
#pragma unroll
            for (int r = 0; r < 4; r++) {
                const int oo = o0 + m * 16 + quad * 4 + r;
                outb[(size_t)oo * HW + ss] = acc[m][n][r] + bias[oo];
            }
        }
}

extern "C" void kernel_launch(void* const* d_in, const int* in_sizes, int n_in,
                              void* d_out, int out_size, void* d_ws, size_t ws_size,
                              hipStream_t stream) {
    const float* x   = (const float*)d_in[0];
    const float* Wq  = (const float*)d_in[1];
    const float* Wkv = (const float*)d_in[2];
    const float* Wo  = (const float*)d_in[3];
    const float* bo  = (const float*)d_in[4];
    float* out = (float*)d_out;

    // ws layout (bf16 elements)
    unsigned short* xT   = (unsigned short*)d_ws;                 // 4*25*12*4096 = 4,915,200
    unsigned short* wT   = xT + (size_t)4915200;                  // 12*12*128*32 =   589,824
    unsigned short* wT3  = wT + (size_t)589824;                   // 3*16*128*32  =   196,608
    unsigned short* qkvT = wT3 + (size_t)196608;                  // 3*4*8*3136*64 = 19,267,584
    unsigned short* aoT  = qkvT + (size_t)(3 * QKV_T);            // 4*49*16*2048 =  6,422,528

    // one merged preprocessing dispatch: 2400 cvtT_x blocks + 384 cvt_w blocks
    cvt_all<<<dim3(2784), 256, 0, stream>>>(x, Wq, Wkv, Wo, xT, wT, wT3);

    gemm1<<<dim3(1200), 256, 0, stream>>>(xT, wT, qkvT);
    natt2<<<dim3(800), 256, 0, stream>>>(qkvT, aoT);
    gemm3<<<dim3(588), 256, 0, stream>>>(aoT, wT3, bo, out);
}

// Round 13
// 128.843 us; speedup vs baseline: 1.0929x; 1.0068x over previous
//
#include <hip/hip_runtime.h>

// ConvAttention2d: B=4, DIM=384, HEADS=8, DH=64, INNER=512, H=W=56, KS=3
// fp32 in/out. Internals: bf16 MFMA GEMMs (fp32 accum), blocked bf16 buffers.
// qkv = x @ [Wq;Wkv] -> 3x3 neighborhood attention -> out = ao @ Wo + bo
// R24: natt2 = 512-thread blocks, (p=t>>1, dq=t&1): 256 positions/block at
// the SAME 32 channels/thread as the proven R18 body (R19's 64ch spilled).
// Halo ratio 1.89 -> 1.45 (370 rows / 256 pos, fetch -11MB); dq-partner is
// lane t^1 so the dot reduce is one __shfl_xor -> dred LDS (9.2KB) and its
// ~27 LDS ops/thread eliminated. Sum order (dq0+dq1) preserved -> bit-exact.
// gemm1 (R23 coalesced epilogue) / gemm3 (R19) / cvt_all (R15) unchanged.

#define HW 3136
#define WIMG 56
#define QKV_CH 1536
#define SCALE 0.125f
#define KSTR 72            // natt LDS row stride in ushorts (144B)
#define NROWS2 370         // staged rows: s0-57 .. s0+312
#define QKV_T 6422528      // one tensor: 4*8*3136*64 bf16 elems

typedef __bf16 bf16x8_t __attribute__((ext_vector_type(8)));
typedef float f32x4_t __attribute__((ext_vector_type(4)));
typedef unsigned short ushort8 __attribute__((ext_vector_type(8)));

__device__ __forceinline__ float bf2f(unsigned short u) {
    return __uint_as_float(((unsigned int)u) << 16);
}
__device__ __forceinline__ unsigned short f2bf(float f) {
    unsigned int u = __float_as_uint(f);
    u += 0x7FFFu + ((u >> 16) & 1u);   // round-to-nearest-even
    return (unsigned short)(u >> 16);
}

// async global->LDS, 16B per lane. LDS dest = wave-uniform base + lane*16.
__device__ __forceinline__ void gll16(const unsigned short* g, unsigned short* l) {
    __builtin_amdgcn_global_load_lds(
        (const __attribute__((address_space(1))) unsigned int*)g,
        (__attribute__((address_space(3))) unsigned int*)l,
        16, 0, 0);
}

// ---------------------------------------------------------------------------
// cvt_all (R15 verbatim): merged preprocessing.
// ---------------------------------------------------------------------------
__global__ __launch_bounds__(256) void cvt_all(
    const float* __restrict__ x,
    const float* __restrict__ Wq, const float* __restrict__ Wkv,
    const float* __restrict__ Wo,
    unsigned short* __restrict__ xT,
    unsigned short* __restrict__ wT, unsigned short* __restrict__ wT3)
{
    __shared__ unsigned short Tl[64 * 36];   // [s][c], pad 36 (cvtT_x branch only)
    const int bx = blockIdx.x;
    const int t = threadIdx.x;

    if (bx < 2400) {
        // ------- cvtT_x body -------
        const int sblk = bx % 50;
        const int kblk = (bx / 50) % 12;
        const int b    = bx / 600;

        if (sblk == 49) {               // zero-fill s in [3136,3200)
            unsigned short* dst = xT + (((size_t)b * 25 + 24) * 12 + kblk) * 4096 + 2048;
            *reinterpret_cast<uint4*>(dst + t * 8) = (uint4){0, 0, 0, 0};
            return;
        }

        const float* xp = x + ((size_t)b * 384 + (size_t)kblk * 32) * HW + sblk * 64;
        const int c = t >> 3;                    // 0..31
#pragma unroll
        for (int i = 0; i < 2; i++) {
            const int sc = (t & 7) + 8 * i;      // 0..15 (float4 chunks)
            const float4 v = *reinterpret_cast<const float4*>(xp + (size_t)c * HW + sc * 4);
            const int s4 = sc * 4;
            Tl[(s4 + 0) * 36 + c] = f2bf(v.x);
            Tl[(s4 + 1) * 36 + c] = f2bf(v.y);
            Tl[(s4 + 2) * 36 + c] = f2bf(v.z);
            Tl[(s4 + 3) * 36 + c] = f2bf(v.w);
        }
        __syncthreads();

        const int row = t >> 2, gran = t & 3;
        const uint2 lo = *reinterpret_cast<const uint2*>(&Tl[row * 36 + gran * 8]);
        const uint2 hi = *reinterpret_cast<const uint2*>(&Tl[row * 36 + gran * 8 + 4]);
        uint4 o; o.x = lo.x; o.y = lo.y; o.z = hi.x; o.w = hi.y;
        unsigned short* dst = xT + (((size_t)b * 25 + (sblk >> 1)) * 12 + kblk) * 4096
                            + (sblk & 1) * 2048;
        *reinterpret_cast<uint4*>(dst + t * 8) = o;
        return;
    }

    // ------- cvt_w body -------
    const int i = (bx - 2400) * 256 + t;
    if (i < 73728) {                    // wT: 12*12*128*4 uint4 slots
        const int g = i & 3;
        const int idx3 = i >> 2;        // [oblk][kb][o128]
        const int o128 = idx3 & 127;
        const int rest = idx3 >> 7;     // 0..143
        const int kb = rest % 12, oblk = rest / 12;
        const int o = oblk * 128 + o128;
        const int k0 = kb * 32 + g * 8;
        const float* src = (o < 512) ? (Wq + (size_t)o * 384 + k0)
                                     : (Wkv + (size_t)(o - 512) * 384 + k0);
        const float4 v0 = *reinterpret_cast<const float4*>(src);
        const float4 v1 = *reinterpret_cast<const float4*>(src + 4);
        uint4 u;
        u.x = (unsigned int)f2bf(v0.x) | ((unsigned int)f2bf(v0.y) << 16);
        u.y = (unsigned int)f2bf(v0.z) | ((unsigned int)f2bf(v0.w) << 16);
        u.z = (unsigned int)f2bf(v1.x) | ((unsigned int)f2bf(v1.y) << 16);
        u.w = (unsigned int)f2bf(v1.z) | ((unsigned int)f2bf(v1.w) << 16);
        reinterpret_cast<uint4*>(wT)[i] = u;
    } else {                            // wT3: 3*16*128*4 = 24576 uint4 slots
        const int j = i - 73728;        // [0, 24576)
        const int g = j & 3;
        const int idx3 = j >> 2;        // 0..6143
        const int o128 = idx3 & 127;
        const int rest = idx3 >> 7;     // 0..47
        const int kb = rest % 16, oblk = rest / 16;
        const int o = oblk * 128 + o128;            // < 384
        const float* src = Wo + (size_t)o * 512 + kb * 32 + g * 8;
        const float4 v0 = *reinterpret_cast<const float4*>(src);
        const float4 v1 = *reinterpret_cast<const float4*>(src + 4);
        uint4 u;
        u.x = (unsigned int)f2bf(v0.x) | ((unsigned int)f2bf(v0.y) << 16);
        u.y = (unsigned int)f2bf(v0.z) | ((unsigned int)f2bf(v0.w) << 16);
        u.z = (unsigned int)f2bf(v1.x) | ((unsigned int)f2bf(v1.y) << 16);
        u.w = (unsigned int)f2bf(v1.z) | ((unsigned int)f2bf(v1.w) << 16);
        reinterpret_cast<uint4*>(wT3)[j] = u;
    }
}

// ---------------------------------------------------------------------------
// GEMM1 (R23 verbatim): R20 K-loop + fixed coalesced epilogue (swizzled LDS
// stage, contiguous global stores). XCD-chunked grid (1200 blocks).
// ---------------------------------------------------------------------------
__global__ __launch_bounds__(256) void gemm1(
    const unsigned short* __restrict__ xT,   // [b][25][12][128][32]
    const unsigned short* __restrict__ wT,   // [12][12][128][32]
    unsigned short* __restrict__ qkvT)       // [3][4][8][3136][64] bf16
{
    __shared__ __align__(16) unsigned short SMEM[16384];   // 32 KB
    unsigned short* A_lds = SMEM;            // [2][4096]
    unsigned short* B_lds = SMEM + 8192;     // [2][4096]

    const int lin = blockIdx.x;              // 0..1199
    const int swz = (lin & 7) * 150 + (lin >> 3);
    const int sblk = swz % 25;
    const int oblk = (swz / 25) % 12;
    const int b    = swz / 300;

    const int t  = threadIdx.x;
    const int lane = t & 63, w = t >> 6;
    const int quad = lane >> 4, mrow = lane & 15;
    const int wm = w >> 1, wn = w & 1;       // wave quadrant

    const unsigned short* wsrc = wT + ((size_t)oblk * 12) * 4096;
    const unsigned short* xsrc = xT + (((size_t)b * 25 + sblk) * 12) * 4096;

    f32x4_t acc[4][4];
#pragma unroll
    for (int m = 0; m < 4; m++)
#pragma unroll
        for (int n = 0; n < 4; n++) acc[m][n] = (f32x4_t){0.f, 0.f, 0.f, 0.f};

    for (int kb = 0; kb < 6; kb++) {
        const size_t k0 = (size_t)(2 * kb) * 4096;
        const size_t k1 = (size_t)(2 * kb + 1) * 4096;
        __syncthreads();   // previous iteration's fragment reads complete
        gll16(wsrc + k0 + t * 8,        A_lds + t * 8);
        gll16(wsrc + k0 + 2048 + t * 8, A_lds + 2048 + t * 8);
        gll16(wsrc + k1 + t * 8,        A_lds + 4096 + t * 8);
        gll16(wsrc + k1 + 2048 + t * 8, A_lds + 6144 + t * 8);
        gll16(xsrc + k0 + t * 8,        B_lds + t * 8);
        gll16(xsrc + k0 + 2048 + t * 8, B_lds + 2048 + t * 8);
        gll16(xsrc + k1 + t * 8,        B_lds + 4096 + t * 8);
        gll16(xsrc + k1 + 2048 + t * 8, B_lds + 6144 + t * 8);
        __syncthreads();   // drains vmcnt(0): both panels ready

#pragma unroll
        for (int ks = 0; ks < 2; ks++) {     // k ascending -> bit-exact
            bf16x8_t af[4], bfr[4];
#pragma unroll
            for (int m = 0; m < 4; m++)
                af[m] = *reinterpret_cast<const bf16x8_t*>(&A_lds[ks * 4096 + (wm * 64 + m * 16 + mrow) * 32 + quad * 8]);
#pragma unroll
            for (int n = 0; n < 4; n++)
                bfr[n] = *reinterpret_cast<const bf16x8_t*>(&B_lds[ks * 4096 + (wn * 64 + n * 16 + mrow) * 32 + quad * 8]);
#pragma unroll
            for (int m = 0; m < 4; m++)
#pragma unroll
                for (int n = 0; n < 4; n++)
                    acc[m][n] = __builtin_amdgcn_mfma_f32_16x16x32_bf16(af[m], bfr[n], acc[m][n], 0, 0, 0);
        }
    }

    // ---- epilogue: stage tile [plane wm][srow 128][d 64] with 16B-chunk
    // XOR-swizzle (chunk ^ (srow&7)); then contiguous global stores.
    __syncthreads();       // all waves done reading staging LDS
#pragma unroll
    for (int m = 0; m < 4; m++) {
        const int chunkw = m * 2 + (quad >> 1);   // d>>3
        const int half   = quad & 1;              // which 8B of the 16B chunk
#pragma unroll
        for (int n = 0; n < 4; n++) {
            const int srow = wn * 64 + n * 16 + mrow;
            unsigned short v[4];
            v[0] = f2bf(acc[m][n][0]); v[1] = f2bf(acc[m][n][1]);
            v[2] = f2bf(acc[m][n][2]); v[3] = f2bf(acc[m][n][3]);
            *reinterpret_cast<uint2*>(&SMEM[wm * 8192 + srow * 64
                + ((chunkw ^ (srow & 7)) << 3) + half * 4])
                = *reinterpret_cast<const uint2*>(v);
        }
    }
    __syncthreads();

    // global: f = i*256+t -> plane f>>10, row (f>>3)&127, chunk f&7.
    // Wave's 64 lanes -> 1KB contiguous qkvT run per instruction.
    const int which = oblk >> 2;
#pragma unroll
    for (int i = 0; i < 8; i++) {
        const int f = i * 256 + t;           // 0..2047
        const int plane = f >> 10;           // 0,1 (= wm of producer)
        const int row   = (f >> 3) & 127;
        const int chunk = f & 7;
        const int hq2 = (oblk & 3) * 2 + plane;
        const int sg  = sblk * 128 + row;
        if (sg < HW) {
            const unsigned short* lsrc = SMEM + plane * 8192 + row * 64
                                       + ((chunk ^ (row & 7)) << 3);
            unsigned short* gdst = qkvT + (size_t)which * QKV_T
                                 + ((size_t)(b * 8 + hq2) * HW + sg) * 64 + chunk * 8;
            *reinterpret_cast<uint4*>(gdst) = *reinterpret_cast<const uint4*>(lsrc);
        }
    }
}

// ---------------------------------------------------------------------------
// Neighborhood attention (R24): 512 threads, p=t>>1 (256 positions), dq=t&1
// (32 channels). Halo 370/256 = 1.45. dq-partner = lane t^1 -> dot reduce
// via __shfl_xor, no dred LDS. K/V time-share one 53.3 KB buffer.
// Grid 416 = 52/XCD exact chunk.
// ---------------------------------------------------------------------------
__global__ __launch_bounds__(512) void natt2(
    const unsigned short* __restrict__ qkvT, // [3][4][8][3136][64] bf16
    unsigned short* __restrict__ aoT)        // [4][49][16][64][32] bf16
{
    __shared__ __align__(16) unsigned short KV[NROWS2 * KSTR]; // 53,280 B

    const int lin = blockIdx.x;          // 0..415
    const int swz = (lin & 7) * 52 + (lin >> 3);
    const int sblk = swz % 13;           // 0..12
    const int h = (swz / 13) & 7;
    const int b = swz / 104;

    const int t = threadIdx.x;           // 0..511
    const int p  = t >> 1;               // position within block (0..255)
    const int dq = t & 1;                // d-half (32 channels)
    const int s0 = sblk * 256;
    const int s  = s0 + p;               // may be >= HW in tail block
    const int sc = min(s, HW - 1);       // clamped for safe loads
    const int y  = sc / WIMG, xx = sc % WIMG;

    const unsigned short* qg = qkvT + ((size_t)(b * 8 + h) * HW) * 64;
    const unsigned short* kg = qg + (size_t)QKV_T;
    const unsigned short* vg = qg + (size_t)(2 * QKV_T);

    // ---- stage K: 370 rows x 8 chunks = 2960 uint4 ----
#pragma unroll
    for (int i = 0; i < 6; i++) {
        const int f = i * 512 + t;
        if (f < NROWS2 * 8) {
            const int row = f >> 3, c8 = f & 7;
            int srow = s0 - 57 + row;
            srow = min(max(srow, 0), HW - 1);
            const uint4 k4 = *reinterpret_cast<const uint4*>(kg + (size_t)srow * 64 + c8 * 8);
            *reinterpret_cast<uint4*>(&KV[row * KSTR + c8 * 8]) = k4;
        }
    }

    int   roff[9];
    float msk[9];
#pragma unroll
    for (int ty = 0; ty < 3; ty++)
#pragma unroll
        for (int tx = 0; tx < 3; tx++) {
            const int tap = ty * 3 + tx;
            const int ny = y + ty - 1, nx = xx + tx - 1;
            const bool v = (ny >= 0) && (ny < WIMG) && (nx >= 0) && (nx < WIMG);
            roff[tap] = (v ? ((ty - 1) * WIMG + (tx - 1)) : 0) * KSTR;
            msk[tap]  = v ? 1.f : 0.f;
        }

    // q: 32 channels for this (pos, dq) — 4 vectorized global loads
    float qv[32];
#pragma unroll
    for (int c = 0; c < 4; c++) {
        const uint4 q4 = *reinterpret_cast<const uint4*>(qg + (size_t)sc * 64 + dq * 32 + c * 8);
        qv[c*8+0] = bf2f((unsigned short)(q4.x & 0xffff)); qv[c*8+1] = bf2f((unsigned short)(q4.x >> 16));
        qv[c*8+2] = bf2f((unsigned short)(q4.y & 0xffff)); qv[c*8+3] = bf2f((unsigned short)(q4.y >> 16));
        qv[c*8+4] = bf2f((unsigned short)(q4.z & 0xffff)); qv[c*8+5] = bf2f((unsigned short)(q4.z >> 16));
        qv[c*8+6] = bf2f((unsigned short)(q4.w & 0xffff)); qv[c*8+7] = bf2f((unsigned short)(q4.w >> 16));
    }

    __syncthreads();                     // K staged

    const int rbase = (57 + p) * KSTR + dq * 32;

    float dots[9];
#pragma unroll
    for (int tp = 0; tp < 9; tp++) dots[tp] = 0.f;
#pragma unroll
    for (int ch = 0; ch < 4; ch++) {
#pragma unroll
        for (int tp = 0; tp < 9; tp++) {
            const ushort8 kk = *reinterpret_cast<const ushort8*>(&KV[rbase + roff[tp] + ch * 8]);
#pragma unroll
            for (int j = 0; j < 8; j++)
                dots[tp] += qv[ch * 8 + j] * bf2f(kk[j]);   // dd ascending per tap
        }
    }

    __syncthreads();                     // dots done: K buffer dead

    // stage V into KV (K region dead)
#pragma unroll
    for (int i = 0; i < 6; i++) {
        const int f = i * 512 + t;
        if (f < NROWS2 * 8) {
            const int row = f >> 3, c8 = f & 7;
            int srow = s0 - 57 + row;
            srow = min(max(srow, 0), HW - 1);
            const uint4 v4 = *reinterpret_cast<const uint4*>(vg + (size_t)srow * 64 + c8 * 8);
            *reinterpret_cast<uint4*>(&KV[row * KSTR + c8 * 8]) = v4;
        }
    }

    __syncthreads();                     // V ready

    // partner sum via shfl (partner = lane t^1, same wave); order dq0+dq1
    float mx = -1e30f, dt[9];
#pragma unroll
    for (int tp = 0; tp < 9; tp++) {
        const float other = __shfl_xor(dots[tp], 1);
        const float lo = dq ? other : dots[tp];     // dq0 partial
        const float hi = dq ? dots[tp] : other;     // dq1 partial
        dt[tp] = msk[tp] * ((lo + hi) * SCALE);
        mx = fmaxf(mx, dt[tp]);
    }
    float se = 0.f, w9[9];
#pragma unroll
    for (int tp = 0; tp < 9; tp++) { w9[tp] = __expf(dt[tp] - mx); se += w9[tp]; }
    const float inv = 1.f / se;
#pragma unroll
    for (int tp = 0; tp < 9; tp++) w9[tp] *= inv * msk[tp];

    // PV: per 8-d chunk load 9 V fragments, accumulate tp-inner
    float o[32];
#pragma unroll
    for (int dd = 0; dd < 32; dd++) o[dd] = 0.f;
#pragma unroll
    for (int ch = 0; ch < 4; ch++) {
        ushort8 vfr[9];
#pragma unroll
        for (int tp = 0; tp < 9; tp++)
            vfr[tp] = *reinterpret_cast<const ushort8*>(&KV[rbase + roff[tp] + ch * 8]);
#pragma unroll
        for (int j = 0; j < 8; j++)
#pragma unroll
            for (int tp = 0; tp < 9; tp++)
                o[ch * 8 + j] += w9[tp] * bf2f(vfr[tp][j]);
    }

    if (s < HW) {
        __align__(16) unsigned short ov[32];
#pragma unroll
        for (int dd = 0; dd < 32; dd++) ov[dd] = f2bf(o[dd]);
        // blocked store: channels c = h*64 + dq*32 .. +32 -> kb = h*2+dq, col 0..32
        unsigned short* dst = aoT + (((size_t)(b * 49 + (s >> 6))) * 16 + (h * 2 + dq)) * 2048
                            + (s & 63) * 32;
        *reinterpret_cast<uint4*>(dst)      = *reinterpret_cast<const uint4*>(ov);
        *reinterpret_cast<uint4*>(dst + 8)  = *reinterpret_cast<const uint4*>(ov + 8);
        *reinterpret_cast<uint4*>(dst + 16) = *reinterpret_cast<const uint4*>(ov + 16);
        *reinterpret_cast<uint4*>(dst + 24) = *reinterpret_cast<const uint4*>(ov + 24);
    }
}

// ---------------------------------------------------------------------------
// GEMM3 (R19 verbatim): BK=64 + bijective XCD-chunked 1D grid (588 blocks,
// 4 XCDs x 74 + 4 XCDs x 73), oblk-fastest work order.
// ---------------------------------------------------------------------------
__global__ __launch_bounds__(256) void gemm3(
    const unsigned short* __restrict__ aoT,  // [4][49][16][64][32]
    const unsigned short* __restrict__ wT3,  // [3][16][128][32]
    const float* __restrict__ bias,          // (384)
    float* __restrict__ out)                 // (4,384,3136) f32
{
    __shared__ __align__(16) unsigned short A_lds[2][128 * 32];
    __shared__ __align__(16) unsigned short B_lds[2][64 * 32];

    // bijective XCD chunk: 588 = 4*74 + 4*73
    const int lin = blockIdx.x;              // 0..587
    const int xcd = lin & 7, idx = lin >> 3;
    const int wid = (xcd < 4) ? (xcd * 74 + idx) : (296 + (xcd - 4) * 73 + idx);
    const int oblk = wid % 3;                // oblk fastest: aoT tile shared
    const int sblk = (wid / 3) % 49;
    const int b    = wid / 147;

    const int t  = threadIdx.x;
    const int lane = t & 63, w = t >> 6;
    const int quad = lane >> 4, mrow = lane & 15;
    const int wm = w >> 1, wn = w & 1;       // wave: 64o x 32s quadrant

    const unsigned short* asrc = wT3 + (size_t)oblk * 16 * 4096;
    const unsigned short* bsrc = aoT + ((size_t)(b * 49 + sblk)) * 16 * 2048;

    f32x4_t acc[4][2];
#pragma unroll
    for (int m = 0; m < 4; m++)
#pragma unroll
        for (int n = 0; n < 2; n++) acc[m][n] = (f32x4_t){0.f, 0.f, 0.f, 0.f};

    for (int kb = 0; kb < 8; kb++) {
        const size_t a0 = (size_t)(2 * kb) * 4096;
        const size_t a1 = (size_t)(2 * kb + 1) * 4096;
        const size_t b0 = (size_t)(2 * kb) * 2048;
        const size_t b1 = (size_t)(2 * kb + 1) * 2048;
        __syncthreads();
        gll16(asrc + a0 + t * 8,        A_lds[0] + t * 8);
        gll16(asrc + a0 + 2048 + t * 8, A_lds[0] + 2048 + t * 8);
        gll16(asrc + a1 + t * 8,        A_lds[1] + t * 8);
        gll16(asrc + a1 + 2048 + t * 8, A_lds[1] + 2048 + t * 8);
        gll16(bsrc + b0 + t * 8,        B_lds[0] + t * 8);
        gll16(bsrc + b1 + t * 8,        B_lds[1] + t * 8);
        __syncthreads();

#pragma unroll
        for (int ks = 0; ks < 2; ks++) {     // k ascending -> bit-exact
            bf16x8_t af[4], bfr[2];
#pragma unroll
            for (int m = 0; m < 4; m++)
                af[m] = *reinterpret_cast<const bf16x8_t*>(&A_lds[ks][(wm * 64 + m * 16 + mrow) * 32 + quad * 8]);
#pragma unroll
            for (int n = 0; n < 2; n++)
                bfr[n] = *reinterpret_cast<const bf16x8_t*>(&B_lds[ks][(wn * 32 + n * 16 + mrow) * 32 + quad * 8]);
#pragma unroll
            for (int m = 0; m < 4; m++)
#pragma unroll
                for (int n = 0; n < 2; n++)
                    acc[m][n] = __builtin_amdgcn_mfma_f32_16x16x32_bf16(af[m], bfr[n], acc[m][n], 0, 0, 0);
        }
    }

    const int o0 = oblk * 128 + wm * 64;
    const int s0 = sblk * 64 + wn * 32;
    float* outb = out + (size_t)b * 384 * HW;
#pragma unroll
    for (int m = 0; m < 4; m++)
#pragma unroll
        for (int n = 0; n < 2; n++) {
            const int ss = s0 + n * 16 + mrow;      // < 3136 always (49*64 exact)
#pragma unroll
            for (int r = 0; r < 4; r++) {
                const int oo = o0 + m * 16 + quad * 4 + r;
                outb[(size_t)oo * HW + ss] = acc[m][n][r] + bias[oo];
            }
        }
}

extern "C" void kernel_launch(void* const* d_in, const int* in_sizes, int n_in,
                              void* d_out, int out_size, void* d_ws, size_t ws_size,
                              hipStream_t stream) {
    const float* x   = (const float*)d_in[0];
    const float* Wq  = (const float*)d_in[1];
    const float* Wkv = (const float*)d_in[2];
    const float* Wo  = (const float*)d_in[3];
    const float* bo  = (const float*)d_in[4];
    float* out = (float*)d_out;

    // ws layout (bf16 elements)
    unsigned short* xT   = (unsigned short*)d_ws;                 // 4*25*12*4096 = 4,915,200
    unsigned short* wT   = xT + (size_t)4915200;                  // 12*12*128*32 =   589,824
    unsigned short* wT3  = wT + (size_t)589824;                   // 3*16*128*32  =   196,608
    unsigned short* qkvT = wT3 + (size_t)196608;                  // 3*4*8*3136*64 = 19,267,584
    unsigned short* aoT  = qkvT + (size_t)(3 * QKV_T);            // 4*49*16*2048 =  6,422,528

    // one merged preprocessing dispatch: 2400 cvtT_x blocks + 384 cvt_w blocks
    cvt_all<<<dim3(2784), 256, 0, stream>>>(x, Wq, Wkv, Wo, xT, wT, wT3);

    gemm1<<<dim3(1200), 256, 0, stream>>>(xT, wT, qkvT);
    natt2<<<dim3(416), 512, 0, stream>>>(qkvT, aoT);
    gemm3<<<dim3(588), 256, 0, stream>>>(aoT, wT3, bo, out);
}